// Round 8
// baseline (89.840 us; speedup 1.0000x reference)
//
#include <hip/hip_runtime.h>
#include <stdint.h>
#include <math.h>

#define BNTH 256           // 4 waves
#define CAP 1024           // max candidates per class-task (M ~ 330 +- 18)
#define MAXK 50
#define THRESH_F 0.05f
#define NMS_T 0.3f
#define SEGW_MAX 32        // 64-row segments per image (N <= 2048; problem: 32)
#define RMAX 8             // SEGW_MAX / 4 waves
#define FG_MAX 24          // max fg classes (problem: 20)
#define NIMG_MAX 32        // max 2*Bimg (problem: 16)

// Decode one (image b, row n, class c) box exactly like the reference.
// (Arithmetic identical to the absmax-0.0 version -- do not reorder.)
__device__ __forceinline__ void decode_box(
    const float* __restrict__ rois, const float* __restrict__ pred,
    float H, float W, float scale,
    int b, int n, int c, int N, int C, float out[4])
{
    const float* r = rois + ((size_t)b * N + n) * 5;
    float bx1 = r[1], by1 = r[2], bx2 = r[3], by2 = r[4];
    float w  = bx2 - bx1 + 1.0f;
    float h  = by2 - by1 + 1.0f;
    float cx = bx1 + 0.5f * w;
    float cy = by1 + 0.5f * h;
    const float* d = pred + ((size_t)b * N + n) * 4 * C + 4 * c;
    float dx = d[0] * 0.1f, dy = d[1] * 0.1f;
    float dw = d[2] * 0.2f, dh = d[3] * 0.2f;
    float pcx = dx * w + cx;
    float pcy = dy * h + cy;
    float pw  = expf(dw) * w;
    float ph  = expf(dh) * h;
    float X1 = fminf(fmaxf(pcx - 0.5f * pw, 0.0f), W - 1.0f);
    float Y1 = fminf(fmaxf(pcy - 0.5f * ph, 0.0f), H - 1.0f);
    float X2 = fminf(fmaxf(pcx + 0.5f * pw, 0.0f), W - 1.0f);
    float Y2 = fminf(fmaxf(pcy + 0.5f * ph, 0.0f), H - 1.0f);
    out[0] = X1 / scale;
    out[1] = Y1 / scale;
    out[2] = X2 / scale;
    out[3] = Y2 / scale;
}

// ONE kernel: one 4-wave block per (stream, image, fg-class).
// collect (pipelined loads + ballot compaction) -> rank sort (all waves,
// no dependency chain) -> decode sorted (all waves) -> wave-0 scan NMS with
// precomputed per-batch 64x64 suppression masks (scalar keep chain) ->
// monotonic-ticket gate: LAST block performs select (top-50 cap) + combine.
__global__ __launch_bounds__(BNTH, 1) void nms_kernel(
    const float* __restrict__ rois_A, const float* __restrict__ cls_A,
    const float* __restrict__ pred_A, const float* __restrict__ info_A,
    const float* __restrict__ rois_B, const float* __restrict__ cls_B,
    const float* __restrict__ pred_B, const float* __restrict__ info_B,
    int Bimg, int N, int C,
    float* __restrict__ kept_scores, int* __restrict__ kcounts,
    float* __restrict__ cls_box,
    unsigned long long* __restrict__ ticket, float* __restrict__ out)
{
    const int FG = C - 1;
    const int bx = blockIdx.x;
    const int st  = bx / (Bimg * FG);
    const int rem = bx % (Bimg * FG);
    const int b = rem / FG;
    const int j = rem % FG;
    const int c = j + 1;
    const int tid = threadIdx.x;
    const int w = tid >> 6;
    const int lane = tid & 63;
    const int SEGW = (N + 63) >> 6;

    const float* rois = st ? rois_B : rois_A;
    const float* cls  = st ? cls_B  : cls_A;
    const float* pred = st ? pred_B : pred_A;
    const float* info = st ? info_B : info_A;

    __shared__ uint64_t segKeys[SEGW_MAX][64];   // reused as sortedK later
    __shared__ int segCnt[SEGW_MAX];
    __shared__ int offL[SEGW_MAX + 1];
    __shared__ uint64_t keysL[CAP];
    __shared__ float4 boxL[CAP];
    __shared__ float  sarL[CAP];
    __shared__ float4 keptL[MAXK];
    __shared__ float  keptSc[MAXK];
    __shared__ int amlastL;
    // select scratch (used only by the last block)
    __shared__ float swSc[4][FG_MAX];
    __shared__ int   swKc[4][FG_MAX];
    __shared__ int   swCnt[4][FG_MAX];
    __shared__ float bestSL[NIMG_MAX][FG_MAX];
    __shared__ float4 bestBL[NIMG_MAX][FG_MAX];

    uint64_t* sortedK = &segKeys[0][0];          // overlay (>= CAP u64)

    // ---- Collect: all loads issued first (pipelined), then ballots ----
    float scv[RMAX];
    #pragma unroll
    for (int r = 0; r < RMAX; ++r) {
        const int seg = w + 4 * r;
        const int n = seg * 64 + lane;
        scv[r] = 0.0f;
        if (seg < SEGW && n < N)
            scv[r] = cls[((size_t)b * N + n) * C + c];
    }
    #pragma unroll
    for (int r = 0; r < RMAX; ++r) {
        const int seg = w + 4 * r;
        if (seg < SEGW) {
            const int n = seg * 64 + lane;
            const bool val = scv[r] > THRESH_F;
            const uint64_t bal = __ballot(val);
            if (val) {
                const int slot = __popcll(bal & ((1ull << lane) - 1ull));
                segKeys[seg][slot] =
                    ((uint64_t)__float_as_uint(scv[r]) << 32) |
                    (uint32_t)(~(uint32_t)n);
            }
            if (lane == 0) segCnt[seg] = __popcll(bal);
        }
    }
    __syncthreads();

    // ---- Segment counts -> exclusive offsets (wave-0 shfl scan) ----
    if (tid < 64) {
        int v = (lane < SEGW) ? segCnt[lane] : 0;
        #pragma unroll
        for (int d = 1; d < 64; d <<= 1) {
            const int o = __shfl_up(v, d);
            if (lane >= d) v += o;
        }
        if (lane < SEGW) offL[lane + 1] = v;
        if (lane == 0) offL[0] = 0;
    }
    __syncthreads();
    const int Mfull = offL[SEGW];
    const int M = Mfull < CAP ? Mfull : CAP;

    // ---- Gather segments -> contiguous keysL (binary search, all waves) ----
    for (int i = tid; i < CAP; i += BNTH) {
        uint64_t k = 0ull;
        if (i < M) {
            int lo = 0, hi = SEGW;
            while (hi - lo > 1) {
                const int mid = (lo + hi) >> 1;
                if (offL[mid] <= i) lo = mid; else hi = mid;
            }
            k = segKeys[lo][i - offL[lo]];
        }
        keysL[i] = k;
    }
    __syncthreads();

    // ---- Rank sort: rank = #{j: key_j > key_i}; zero dependency chain ----
    // Keys reinterpreted as positive doubles (order-isomorphic, never NaN).
    {
        const double d0 = __longlong_as_double((long long)keysL[tid]);
        const double d1 = __longlong_as_double((long long)keysL[tid + 256]);
        const double d2 = __longlong_as_double((long long)keysL[tid + 512]);
        const double d3 = __longlong_as_double((long long)keysL[tid + 768]);
        int r0 = 0, r1 = 0, r2 = 0, r3 = 0;
        if (M <= 512) {
            #pragma unroll 4
            for (int jj = 0; jj < M; ++jj) {
                const double dj = __longlong_as_double((long long)keysL[jj]);
                r0 += (dj > d0) ? 1 : 0;
                r1 += (dj > d1) ? 1 : 0;
            }
        } else {
            #pragma unroll 4
            for (int jj = 0; jj < M; ++jj) {
                const double dj = __longlong_as_double((long long)keysL[jj]);
                r0 += (dj > d0) ? 1 : 0;
                r1 += (dj > d1) ? 1 : 0;
                r2 += (dj > d2) ? 1 : 0;
                r3 += (dj > d3) ? 1 : 0;
            }
        }
        if (tid < M)       sortedK[r0] = (uint64_t)__double_as_longlong(d0);
        if (tid + 256 < M) sortedK[r1] = (uint64_t)__double_as_longlong(d1);
        if (tid + 512 < M) sortedK[r2] = (uint64_t)__double_as_longlong(d2);
        if (tid + 768 < M) sortedK[r3] = (uint64_t)__double_as_longlong(d3);
    }
    __syncthreads();

    // ---- Decode in SORTED order, all 4 waves ----
    const float H = info[b * 3 + 0];
    const float W = info[b * 3 + 1];
    const float scale = info[b * 3 + 2];
    for (int i = tid; i < M; i += BNTH) {
        const uint64_t u = sortedK[i];
        const int n = (int)(~(uint32_t)u);
        float o[4];
        decode_box(rois, pred, H, W, scale, b, n, c, N, C, o);
        boxL[i] = make_float4(o[0], o[1], o[2], o[3]);
        sarL[i] = (o[2] - o[0] + 1.0f) * (o[3] - o[1] + 1.0f);
    }
    __syncthreads();

    // ---- Scan NMS (wave 0): per-batch parallel mask build, scalar keeps ----
    if (tid < 64) {
        int kcount = 0;
        for (int s = 0; s * 64 < M && kcount < MAXK; ++s) {
            const int ii = s * 64 + lane;
            const bool valid = (ii < M);
            float cx1 = 0.f, cy1 = 0.f, cx2 = 0.f, cy2 = 0.f;
            float car = 1.0f, csc = 0.f;
            if (valid) {
                const float4 cb4 = boxL[ii];
                cx1 = cb4.x; cy1 = cb4.y; cx2 = cb4.z; cy2 = cb4.w;
                car = sarL[ii];
                csc = __uint_as_float((uint32_t)(sortedK[ii] >> 32));
            }
            // Pre-suppression vs already-kept boxes (pipelined via unroll).
            bool sup = !valid;
            #pragma unroll 4
            for (int q = 0; q < kcount; ++q) {
                const float4 kb = keptL[q];
                const float kar = (kb.z - kb.x + 1.0f) * (kb.w - kb.y + 1.0f);
                const float ix1 = fmaxf(kb.x, cx1), iy1 = fmaxf(kb.y, cy1);
                const float ix2 = fminf(kb.z, cx2), iy2 = fminf(kb.w, cy2);
                const float iw = fmaxf(ix2 - ix1 + 1.0f, 0.0f);
                const float ih = fmaxf(iy2 - iy1 + 1.0f, 0.0f);
                const float inter = iw * ih;
                sup = sup || (inter / (kar + car - inter) > NMS_T);
            }
            // Parallel 64x64 suppression-mask build (lane i suppresses bit j).
            // Garbage rows (>= M) only affect never-alive lanes -- harmless.
            uint64_t smask = 0ull;
            #pragma unroll 16
            for (int jj = 0; jj < 64; ++jj) {
                const float4 bj = boxL[s * 64 + jj];
                const float jar = sarL[s * 64 + jj];
                const float ix1 = fmaxf(cx1, bj.x), iy1 = fmaxf(cy1, bj.y);
                const float ix2 = fminf(cx2, bj.z), iy2 = fminf(cy2, bj.w);
                const float iw = fmaxf(ix2 - ix1 + 1.0f, 0.0f);
                const float ih = fmaxf(iy2 - iy1 + 1.0f, 0.0f);
                const float inter = iw * ih;
                const float iou = inter / (car + jar - inter);
                smask |= (iou > NMS_T) ? (1ull << jj) : 0ull;
            }
            const uint32_t mlo = (uint32_t)smask;
            const uint32_t mhi = (uint32_t)(smask >> 32);

            uint64_t alive = __ballot(valid && !sup);
            // Scalar keep chain: ctz + readlane + andn2 per keep (~25 cy).
            while (alive != 0ull && kcount < MAXK) {
                int l = __builtin_ctzll(alive);
                l = __builtin_amdgcn_readfirstlane(l);
                const uint32_t klo = (uint32_t)__builtin_amdgcn_readlane((int)mlo, l);
                const uint32_t khi = (uint32_t)__builtin_amdgcn_readlane((int)mhi, l);
                const uint64_t ml = ((uint64_t)khi << 32) | klo;
                if (lane == l) {
                    keptL[kcount] = make_float4(cx1, cy1, cx2, cy2);
                    keptSc[kcount] = csc;
                }
                alive &= ~ml;                 // removes l (self-bit) + suppressed
                alive &= ~(1ull << l);        // safety: keeper always removed
                kcount++;
            }
        }
        // ---- flush ----
        if (lane < kcount) kept_scores[(size_t)bx * MAXK + lane] = keptSc[lane];
        if (lane == 0) {
            kcounts[bx] = kcount;
            float4 cb = (kcount > 0) ? keptL[0] : make_float4(0.f, 0.f, 0.f, 0.f);
            *(float4*)(cls_box + (size_t)bx * 4) = cb;
        }
    }
    __syncthreads();

    // ---- Monotonic-ticket gate: last finished block does select+combine ----
    __threadfence();
    if (tid == 0) {
        const unsigned long long t = atomicAdd(ticket, 1ull);
        amlastL = ((t % (unsigned long long)gridDim.x) ==
                   (unsigned long long)(gridDim.x - 1)) ? 1 : 0;
    }
    __syncthreads();
    if (!amlastL) return;
    __threadfence();   // acquire: all blocks' outputs now visible

    // ---- Select: wave w handles images w, w+4, ... (no barriers inside) ----
    const int nimg = 2 * Bimg;
    for (int img = w; img < nimg; img += 4) {
        int kc_l = 0; float sv_l = -INFINITY;
        if (lane < FG) {
            kc_l = kcounts[img * FG + lane];
            if (kc_l > 0) sv_l = kept_scores[((size_t)img * FG + lane) * MAXK];
            swKc[w][lane] = kc_l;
            swSc[w][lane] = sv_l;
            swCnt[w][lane] = 0;
        }
        // Count entries strictly greater than each class's best.
        // Kept lists are sorted desc -> break at first !greater.
        for (int p = lane; p < FG * FG; p += 64) {
            const int cc = p / FG, c2 = p % FG;
            const float sc = swSc[w][cc];
            const int k2 = swKc[w][c2];
            int cnt = 0;
            if (swKc[w][cc] > 0) {
                const float* kp = kept_scores + ((size_t)img * FG + c2) * MAXK;
                for (int k = 0; k < k2; ++k) {
                    const float v = kp[k];
                    const bool greater = (v > sc) || (v == sc && c2 < cc);
                    if (!greater) break;
                    cnt++;
                }
            }
            if (cnt) atomicAdd(&swCnt[w][cc], cnt);
        }
        // Global best detection (max score, ties -> lower class).
        uint32_t mu = 0u;
        if (lane < FG && kc_l > 0) {
            const uint32_t bb = __float_as_uint(sv_l);
            mu = (bb & 0x80000000u) ? ~bb : (bb | 0x80000000u);
        }
        uint64_t gkey = (mu == 0u) ? 0ull
                        : (((uint64_t)mu << 8) | (uint64_t)(255 - lane));
        #pragma unroll
        for (int m = 1; m < 64; m <<= 1) {
            const uint64_t o = __shfl_xor(gkey, m);
            if (o > gkey) gkey = o;
        }
        float4 gbox;
        if ((gkey >> 8) != 0ull) {
            const int g = 255 - (int)(gkey & 0xFFull);
            gbox = *(const float4*)(cls_box + ((size_t)img * FG + g) * 4);
        } else {
            const int st2 = img >= Bimg;
            const int b2  = img - st2 * Bimg;
            const float* rois2 = st2 ? rois_B : rois_A;
            const float* pred2 = st2 ? pred_B : pred_A;
            const float* info2 = st2 ? info_B : info_A;
            float o[4];
            decode_box(rois2, pred2, info2[b2 * 3], info2[b2 * 3 + 1],
                       info2[b2 * 3 + 2], b2, 0, 1, N, C, o);
            gbox = make_float4(o[0], o[1], o[2], o[3]);
        }
        if (lane < FG) {
            const int total = swCnt[w][lane];
            const bool in = (kc_l > 0 && total < MAXK);
            bestSL[img][lane] = in ? sv_l : -INFINITY;
            bestBL[img][lane] = in
                ? *(const float4*)(cls_box + ((size_t)img * FG + lane) * 4)
                : gbox;
        }
    }
    __syncthreads();

    // ---- Combine (wave 0): joint = sA*sB (IEEE -inf*-inf=+inf), argmax ----
    if (tid < Bimg) {
        const int i = tid;
        float bj = 0.0f;
        int cls_ = 0;
        for (int cc = 0; cc < FG; ++cc) {
            const float v = bestSL[i][cc] * bestSL[Bimg + i][cc];
            if (cc == 0 || v > bj) { bj = v; cls_ = cc; }
        }
        const float4 bA = bestBL[i][cls_];
        const float4 bB = bestBL[Bimg + i][cls_];
        out[i * 4 + 0] = bA.x; out[i * 4 + 1] = bA.y;
        out[i * 4 + 2] = bA.z; out[i * 4 + 3] = bA.w;
        out[Bimg * 4 + i * 4 + 0] = bB.x; out[Bimg * 4 + i * 4 + 1] = bB.y;
        out[Bimg * 4 + i * 4 + 2] = bB.z; out[Bimg * 4 + i * 4 + 3] = bB.w;
    }
}

extern "C" void kernel_launch(void* const* d_in, const int* in_sizes, int n_in,
                              void* d_out, int out_size, void* d_ws, size_t ws_size,
                              hipStream_t stream) {
    const float* rois_A = (const float*)d_in[0];
    const float* cls_A  = (const float*)d_in[1];
    const float* pred_A = (const float*)d_in[2];
    const float* info_A = (const float*)d_in[3];
    const float* rois_B = (const float*)d_in[4];
    const float* cls_B  = (const float*)d_in[5];
    const float* pred_B = (const float*)d_in[6];
    const float* info_B = (const float*)d_in[7];
    float* out = (float*)d_out;

    const int Bimg = in_sizes[3] / 3;                  // 8
    const int N    = in_sizes[0] / (Bimg * 5);         // 2000
    const int C    = in_sizes[1] / (Bimg * N);         // 21
    const int FG   = C - 1;                            // 20
    const int NSB  = 2 * Bimg * FG;                    // 320 tasks

    // Workspace: ticket (monotonic, never reset -- residues cycle exactly
    // once per call), then per-task outputs (fully rewritten every call).
    char* ws = (char*)d_ws;
    unsigned long long* ticket = (unsigned long long*)ws;
    size_t off = 256;
    float* kept_scores = (float*)(ws + off);               // [320][50]
    off += (size_t)NSB * MAXK * sizeof(float);
    int* kcounts = (int*)(ws + off);                       // [320]
    off += (size_t)NSB * sizeof(int);
    float* cls_box = (float*)(ws + off);                   // [320][4] (16B aligned)

    nms_kernel<<<NSB, BNTH, 0, stream>>>(
        rois_A, cls_A, pred_A, info_A,
        rois_B, cls_B, pred_B, info_B,
        Bimg, N, C, kept_scores, kcounts, cls_box, ticket, out);
}